// Round 4
// baseline (587.396 us; speedup 1.0000x reference)
//
#include <hip/hip_runtime.h>

#define T_LEN 16384
#define N_TOT 131072          // 8 * 16384
#define ROWS 64               // timesteps per block
#define XROWS 68              // ROWS + DIL(4) history rows
#define XPITCH 136            // 128 + 8 pad (row stride 68 dwords; %32==4 -> 2-way, free)
#define MPITCH 264            // 256 + 8 pad (row stride 132 dwords; %32==4 -> 2-way, free)

typedef __attribute__((ext_vector_type(8))) short short8;
typedef __attribute__((ext_vector_type(4))) short short4v;
typedef __attribute__((ext_vector_type(4))) float floatx4;
typedef unsigned short ushort_t;

__device__ __forceinline__ ushort_t f2bf(float f) {
    unsigned int u = __float_as_uint(f);
    u += 0x7fffu + ((u >> 16) & 1u);        // RNE
    return (ushort_t)(u >> 16);
}

// Repack fp32 weights into bf16 [kc][n][kk32] so each lane's MFMA B-fragment
// (B[k=quad*8+j][n=l16]) is one contiguous 16B load.
// W1: K=256 (k<128: tap1 = x[t]; k>=128: tap0 = x[t-4]), N=512 (tanh | sig)
// W2: K=256 (merged ch), N=384 (res 128 | skip 256)
__global__ void repack_w(const float* __restrict__ w_tanh,
                         const float* __restrict__ w_sig,
                         const float* __restrict__ w_res,
                         const float* __restrict__ w_skip,
                         ushort_t* __restrict__ w1,
                         ushort_t* __restrict__ w2) {
    int i = blockIdx.x * 256 + threadIdx.x;
    if (i < 8 * 512 * 32) {
        int kk = i & 31;
        int n  = (i >> 5) & 511;
        int kc = i >> 14;
        int k  = kc * 32 + kk;
        int tap = (k < 128) ? 1 : 0;
        int cin = k & 127;
        float v = (n < 256) ? w_tanh[(tap * 128 + cin) * 256 + n]
                            : w_sig [(tap * 128 + cin) * 256 + (n - 256)];
        w1[i] = f2bf(v);
    } else {
        int j = i - 8 * 512 * 32;
        if (j < 8 * 384 * 32) {
            int kk = j & 31;
            int n  = (j >> 5) % 384;
            int kc = j / (384 * 32);
            int k  = kc * 32 + kk;
            float v = (n < 128) ? w_res[k * 128 + n]
                                : w_skip[k * 256 + (n - 128)];
            w2[j] = f2bf(v);
        }
    }
}

// Occupancy-targeted restructure v4 (v3 + audit cleanup):
// - ct loops are REAL loops (#pragma unroll 1): live accumulator set per slice
//   is 32 VGPR (GEMM1) / 16 VGPR (GEMM2) instead of the fused 64/48, so the
//   kernel fits __launch_bounds__(512,4) without spill -> 2 blocks/CU
//   (LDS 51.1 KB * 2 = 102 KB < 160 KB). One block's MFMA hides the other's
//   barrier drain + L2 weight latency.
// - T14 issue-early: GEMM2 ct=0's first 4 weight fragments are loaded BEFORE
//   the second barrier; the compiler's vmcnt(0)-before-s_barrier drain means
//   they land while other waves finish their gate phase.
// - v4 fix: GEMM2 ct=0 is explicitly PEELED so pre[]'s live range provably
//   ends there (v3 kept 32 VGPR live across all 3 ct iterations and put a
//   runtime ct==0 branch in the hot kc body).
// - Nontemporal epilogue stores: out (201 MB, write-once) stops evicting the
//   448 KB repacked-weight working set from per-XCD L2.
__global__ __launch_bounds__(512, 4)
void fused_block(const float* __restrict__ x,
                 const float* __restrict__ b_tanh,
                 const float* __restrict__ b_sig,
                 const float* __restrict__ b_res,
                 const float* __restrict__ b_skip,
                 const ushort_t* __restrict__ w1,
                 const ushort_t* __restrict__ w2,
                 float* __restrict__ out) {
    __shared__ ushort_t xbuf[XROWS * XPITCH];
    __shared__ ushort_t mbuf[ROWS * MPITCH];

    const int tid = threadIdx.x;
    const int n0  = blockIdx.x * ROWS;        // flat row base (b*T + t0)
    const int t0  = n0 & (T_LEN - 1);         // within-batch t (64 | 16384)

    // ---- stage X rows [t0-4, t0+64) into LDS, fp32 -> bf16 ----
    for (int idx = tid; idx < XROWS * 32; idx += 512) {
        int r  = idx >> 5;
        int c4 = (idx & 31) << 2;
        int t  = t0 - 4 + r;
        short4v s;
        if (t >= 0) {
            floatx4 v = *(const floatx4*)(x + (size_t)(n0 - 4 + r) * 128 + c4);
            s = short4v{(short)f2bf(v[0]), (short)f2bf(v[1]),
                        (short)f2bf(v[2]), (short)f2bf(v[3])};
        } else {
            s = short4v{0, 0, 0, 0};
        }
        *(short4v*)(xbuf + r * XPITCH + c4) = s;
    }
    __syncthreads();

    const int w    = tid >> 6;
    const int lane = tid & 63;
    const int quad = lane >> 4;
    const int l16  = lane & 15;

    const floatx4 zero4 = {0.f, 0.f, 0.f, 0.f};

    // ---- GEMM1: [64 x 256] x [256 x 512]; wave w owns tanh/sig cols [32w, 32w+32) ----
    // ct is a REAL loop: bounds the live register set to one column slice.
    #pragma unroll 1
    for (int ct = 0; ct < 2; ++ct) {
        floatx4 acc_t[4], acc_s[4];
        #pragma unroll
        for (int rt = 0; rt < 4; ++rt) { acc_t[rt] = zero4; acc_s[rt] = zero4; }

        const int n_t = 32 * w + ct * 16 + l16;   // tanh col (sig col = n_t+256)

        #pragma unroll
        for (int kc = 0; kc < 8; ++kc) {
            const int colb = (kc & 3) * 32 + quad * 8;
            const int roff = (kc < 4) ? 4 : 0;    // kc<4: x[t] (buffer row r+4); else x[t-4]
            short8 a[4];
            #pragma unroll
            for (int rt = 0; rt < 4; ++rt)
                a[rt] = *(const short8*)(xbuf + (rt * 16 + l16 + roff) * XPITCH + colb);
            short8 bt = *(const short8*)(w1 + ((kc * 512 + n_t)       * 32) + quad * 8);
            short8 bs = *(const short8*)(w1 + ((kc * 512 + n_t + 256) * 32) + quad * 8);
            #pragma unroll
            for (int rt = 0; rt < 4; ++rt) {
                acc_t[rt] = __builtin_amdgcn_mfma_f32_16x16x32_bf16(a[rt], bt, acc_t[rt], 0, 0, 0);
                acc_s[rt] = __builtin_amdgcn_mfma_f32_16x16x32_bf16(a[rt], bs, acc_s[rt], 0, 0, 0);
            }
        }

        // ---- gate for this ct: merged = tanh(pt) * sigmoid(ps), bf16 -> LDS ----
        const float btb = b_tanh[n_t];
        const float bsb = b_sig[n_t];
        #pragma unroll
        for (int rt = 0; rt < 4; ++rt)
            #pragma unroll
            for (int i = 0; i < 4; ++i) {
                float pt = acc_t[rt][i] + btb;
                float ps = acc_s[rt][i] + bsb;
                float e2 = __expf(2.0f * pt);
                float th = 1.0f - 2.0f / (e2 + 1.0f);     // stable tanh
                float sg = 1.0f / (1.0f + __expf(-ps));
                int row = rt * 16 + quad * 4 + i;          // C/D: col=l16, row=quad*4+reg
                mbuf[row * MPITCH + n_t] = f2bf(th * sg);
            }
    }

    // ---- T14 issue-early: prefetch GEMM2 ct=0 weights (kc=0..3) before the
    // barrier. vmcnt(0)-before-s_barrier means they complete while other
    // waves finish their gate writes. 4 x short8 = 32 VGPR, consumed entirely
    // by the peeled ct=0 body below.
    const int n2p = 48 * w + l16;
    short8 pre[4];
    #pragma unroll
    for (int kc = 0; kc < 4; ++kc)
        pre[kc] = *(const short8*)(w2 + (kc * 384 + n2p) * 32 + quad * 8);

    __syncthreads();

    // ---- GEMM2: [64 x 256] x [256 x 384]; wave w owns cols [48w, 48w+48) ----
    // Shared epilogue (one copy to audit): res cols [0,128): +b_res + x;
    // skip cols [128,384): +b_skip. col range per (w,ct) is a 16-aligned
    // block -> branch is wave-uniform. Nontemporal: out is write-once.
    auto epilogue = [&](const floatx4 (&acc2)[4], int col) {
        if (col < 128) {
            float bb = b_res[col];
            #pragma unroll
            for (int rt = 0; rt < 4; ++rt)
                #pragma unroll
                for (int i = 0; i < 4; ++i) {
                    int row = rt * 16 + quad * 4 + i;
                    size_t g = (size_t)(n0 + row);
                    __builtin_nontemporal_store(acc2[rt][i] + bb + x[g * 128 + col],
                                                &out[g * 128 + col]);
                }
        } else {
            int c2 = col - 128;
            float bb = b_skip[c2];
            #pragma unroll
            for (int rt = 0; rt < 4; ++rt)
                #pragma unroll
                for (int i = 0; i < 4; ++i) {
                    int row = rt * 16 + quad * 4 + i;
                    size_t g = (size_t)(n0 + row);
                    __builtin_nontemporal_store(acc2[rt][i] + bb,
                                                &out[(size_t)N_TOT * 128 + g * 256 + c2]);
                }
        }
    };

    // ---- ct = 0 (peeled): consumes pre[], live range ends here ----
    {
        floatx4 acc2[4];
        #pragma unroll
        for (int rt = 0; rt < 4; ++rt) acc2[rt] = zero4;

        #pragma unroll
        for (int kc = 0; kc < 8; ++kc) {
            short8 a[4];
            #pragma unroll
            for (int rt = 0; rt < 4; ++rt)
                a[rt] = *(const short8*)(mbuf + (rt * 16 + l16) * MPITCH + kc * 32 + quad * 8);
            short8 b = (kc < 4) ? pre[kc]   // kc compile-time (unrolled) -> static index
                                : *(const short8*)(w2 + (kc * 384 + n2p) * 32 + quad * 8);
            #pragma unroll
            for (int rt = 0; rt < 4; ++rt)
                acc2[rt] = __builtin_amdgcn_mfma_f32_16x16x32_bf16(a[rt], b, acc2[rt], 0, 0, 0);
        }
        epilogue(acc2, n2p);
    }

    // ---- ct = 1..2: REAL loop, branch-free body, 16-VGPR accumulator ----
    #pragma unroll 1
    for (int ct = 1; ct < 3; ++ct) {
        floatx4 acc2[4];
        #pragma unroll
        for (int rt = 0; rt < 4; ++rt) acc2[rt] = zero4;

        const int n2 = 48 * w + ct * 16 + l16;

        #pragma unroll
        for (int kc = 0; kc < 8; ++kc) {
            short8 a[4];
            #pragma unroll
            for (int rt = 0; rt < 4; ++rt)
                a[rt] = *(const short8*)(mbuf + (rt * 16 + l16) * MPITCH + kc * 32 + quad * 8);
            short8 b = *(const short8*)(w2 + (kc * 384 + n2) * 32 + quad * 8);
            #pragma unroll
            for (int rt = 0; rt < 4; ++rt)
                acc2[rt] = __builtin_amdgcn_mfma_f32_16x16x32_bf16(a[rt], b, acc2[rt], 0, 0, 0);
        }
        epilogue(acc2, n2);
    }
}

extern "C" void kernel_launch(void* const* d_in, const int* in_sizes, int n_in,
                              void* d_out, int out_size, void* d_ws, size_t ws_size,
                              hipStream_t stream) {
    const float* x      = (const float*)d_in[0];
    const float* w_tanh = (const float*)d_in[1];
    const float* b_tanh = (const float*)d_in[2];
    const float* w_sig  = (const float*)d_in[3];
    const float* b_sig  = (const float*)d_in[4];
    const float* w_res  = (const float*)d_in[5];
    const float* b_res  = (const float*)d_in[6];
    const float* w_skip = (const float*)d_in[7];
    const float* b_skip = (const float*)d_in[8];

    ushort_t* w1 = (ushort_t*)d_ws;            // 8*512*32 = 131072 bf16 (256 KB)
    ushort_t* w2 = w1 + 8 * 512 * 32;          // 8*384*32 =  98304 bf16 (192 KB)
    float* out = (float*)d_out;

    // 131072 + 98304 = 229376 threads
    repack_w<<<896, 256, 0, stream>>>(w_tanh, w_sig, w_res, w_skip, w1, w2);
    fused_block<<<N_TOT / ROWS, 512, 0, stream>>>(x, b_tanh, b_sig, b_res, b_skip, w1, w2, out);
}

// Round 9
// 430.571 us; speedup vs baseline: 1.3642x; 1.3642x over previous
//
#include <hip/hip_runtime.h>

#define T_LEN 16384
#define N_TOT 131072          // 8 * 16384
#define ROWS 64               // timesteps per block
#define XROWS 68              // ROWS + DIL(4) history rows
#define XPITCH 136            // 128 + 8 pad (row stride 68 dwords; %32==4 -> 2-way, free)
#define MPITCH 264            // 256 + 8 pad (row stride 132 dwords; %32==4 -> 2-way, free)
#define OPITCH 132            // fp32 out-staging pitch: 128 + 4 (2-way max, free)

typedef __attribute__((ext_vector_type(8))) short short8;
typedef __attribute__((ext_vector_type(4))) short short4v;
typedef __attribute__((ext_vector_type(4))) float floatx4;
typedef unsigned short ushort_t;

__device__ __forceinline__ ushort_t f2bf(float f) {
    unsigned int u = __float_as_uint(f);
    u += 0x7fffu + ((u >> 16) & 1u);        // RNE
    return (ushort_t)(u >> 16);
}

// Repack fp32 weights into bf16 [kc][n][kk32] so each lane's MFMA B-fragment
// (B[k=quad*8+j][n=l16]) is one contiguous 16B load.
// W1: K=256 (k<128: tap1 = x[t]; k>=128: tap0 = x[t-4]), N=512 (tanh | sig)
// W2: K=256 (merged ch), N=384 (res 128 | skip 256)
__global__ void repack_w(const float* __restrict__ w_tanh,
                         const float* __restrict__ w_sig,
                         const float* __restrict__ w_res,
                         const float* __restrict__ w_skip,
                         ushort_t* __restrict__ w1,
                         ushort_t* __restrict__ w2) {
    int i = blockIdx.x * 256 + threadIdx.x;
    if (i < 8 * 512 * 32) {
        int kk = i & 31;
        int n  = (i >> 5) & 511;
        int kc = i >> 14;
        int k  = kc * 32 + kk;
        int tap = (k < 128) ? 1 : 0;
        int cin = k & 127;
        float v = (n < 256) ? w_tanh[(tap * 128 + cin) * 256 + n]
                            : w_sig [(tap * 128 + cin) * 256 + (n - 256)];
        w1[i] = f2bf(v);
    } else {
        int j = i - 8 * 512 * 32;
        if (j < 8 * 384 * 32) {
            int kk = j & 31;
            int n  = (j >> 5) % 384;
            int kc = j / (384 * 32);
            int k  = kc * 32 + kk;
            float v = (n < 128) ? w_res[k * 128 + n]
                                : w_skip[k * 256 + (n - 128)];
            w2[j] = f2bf(v);
        }
    }
}

// v5.1: traffic-targeted epilogue restructure (v5) + audit cleanup.
// Round-4 counters: FETCH 660 MB / WRITE 880 MB per dispatch vs ideal
// ~200/201 MB -- 4.4x amplification from half-line (64 B) scattered epilogue
// stores (the two halves of every 128 B line owned by different wave/ct
// slices) made worse by NT partial-line RMW. MfmaUtil 6%, VALUBusy 14%:
// memory-path bound, not occupancy.
// Fix: GEMM2 runs as 3 column-plane passes (pass 0 = res cols 0..127,
// pass 1/2 = skip halves). Each pass stages its 64x128 fp32 result (+bias)
// in LDS (obuf, overlaid on dead xbuf), then all 512 threads stream it out
// as dense float4 full-line NT stores; res pass re-reads x coalesced.
// v5.1: dropped the pre[] GEMM2 weight prefetch -- it reintroduced the
// round-3 cross-iteration liveness bug (32 VGPR pinned across all 3 passes
// + runtime branch in the hot kc body) to hide ~0.15 us of L2 latency per
// block. Branch-free pass loop instead.
// LDS 67.6 KB -> still 2 blocks/CU.
__global__ __launch_bounds__(512, 4)
void fused_block(const float* __restrict__ x,
                 const float* __restrict__ b_tanh,
                 const float* __restrict__ b_sig,
                 const float* __restrict__ b_res,
                 const float* __restrict__ b_skip,
                 const ushort_t* __restrict__ w1,
                 const ushort_t* __restrict__ w2,
                 float* __restrict__ out) {
    // xbuf (18.5 KB, dead after GEMM1) overlaid with obuf (33.8 KB fp32 staging)
    __shared__ __align__(16) unsigned char smem0[ROWS * OPITCH * 4];  // 33792 B
    __shared__ ushort_t mbuf[ROWS * MPITCH];                          // 33792 B
    ushort_t* xbuf = (ushort_t*)smem0;
    float*    obuf = (float*)smem0;

    const int tid = threadIdx.x;
    const int n0  = blockIdx.x * ROWS;        // flat row base (b*T + t0)
    const int t0  = n0 & (T_LEN - 1);         // within-batch t (64 | 16384)

    // ---- stage X rows [t0-4, t0+64) into LDS, fp32 -> bf16 ----
    for (int idx = tid; idx < XROWS * 32; idx += 512) {
        int r  = idx >> 5;
        int c4 = (idx & 31) << 2;
        int t  = t0 - 4 + r;
        short4v s;
        if (t >= 0) {
            floatx4 v = *(const floatx4*)(x + (size_t)(n0 - 4 + r) * 128 + c4);
            s = short4v{(short)f2bf(v[0]), (short)f2bf(v[1]),
                        (short)f2bf(v[2]), (short)f2bf(v[3])};
        } else {
            s = short4v{0, 0, 0, 0};
        }
        *(short4v*)(xbuf + r * XPITCH + c4) = s;
    }
    __syncthreads();

    const int w    = tid >> 6;
    const int lane = tid & 63;
    const int quad = lane >> 4;
    const int l16  = lane & 15;

    const floatx4 zero4 = {0.f, 0.f, 0.f, 0.f};

    // ---- GEMM1: [64 x 256] x [256 x 512]; wave w owns tanh/sig cols [32w, 32w+32) ----
    // ct is a REAL loop: bounds the live register set to one column slice.
    #pragma unroll 1
    for (int ct = 0; ct < 2; ++ct) {
        floatx4 acc_t[4], acc_s[4];
        #pragma unroll
        for (int rt = 0; rt < 4; ++rt) { acc_t[rt] = zero4; acc_s[rt] = zero4; }

        const int n_t = 32 * w + ct * 16 + l16;   // tanh col (sig col = n_t+256)

        #pragma unroll
        for (int kc = 0; kc < 8; ++kc) {
            const int colb = (kc & 3) * 32 + quad * 8;
            const int roff = (kc < 4) ? 4 : 0;    // kc<4: x[t] (buffer row r+4); else x[t-4]
            short8 a[4];
            #pragma unroll
            for (int rt = 0; rt < 4; ++rt)
                a[rt] = *(const short8*)(xbuf + (rt * 16 + l16 + roff) * XPITCH + colb);
            short8 bt = *(const short8*)(w1 + ((kc * 512 + n_t)       * 32) + quad * 8);
            short8 bs = *(const short8*)(w1 + ((kc * 512 + n_t + 256) * 32) + quad * 8);
            #pragma unroll
            for (int rt = 0; rt < 4; ++rt) {
                acc_t[rt] = __builtin_amdgcn_mfma_f32_16x16x32_bf16(a[rt], bt, acc_t[rt], 0, 0, 0);
                acc_s[rt] = __builtin_amdgcn_mfma_f32_16x16x32_bf16(a[rt], bs, acc_s[rt], 0, 0, 0);
            }
        }

        // ---- gate for this ct: merged = tanh(pt) * sigmoid(ps), bf16 -> LDS ----
        const float btb = b_tanh[n_t];
        const float bsb = b_sig[n_t];
        #pragma unroll
        for (int rt = 0; rt < 4; ++rt)
            #pragma unroll
            for (int i = 0; i < 4; ++i) {
                float pt = acc_t[rt][i] + btb;
                float ps = acc_s[rt][i] + bsb;
                float e2 = __expf(2.0f * pt);
                float th = 1.0f - 2.0f / (e2 + 1.0f);     // stable tanh
                float sg = 1.0f / (1.0f + __expf(-ps));
                int row = rt * 16 + quad * 4 + i;          // C/D: col=l16, row=quad*4+reg
                mbuf[row * MPITCH + n_t] = f2bf(th * sg);
            }
    }

    __syncthreads();   // gate writes done; also: xbuf reads done -> obuf writes allowed

    const int cw = 16 * w + l16;              // wave's plane-local column

    // ---- GEMM2 as 3 column-plane passes; wave w owns plane cols [16w,16w+16) ----
    // pass 0: res (global cols 0..127); pass 1: skip 0..127; pass 2: skip 128..255.
    #pragma unroll 1
    for (int p = 0; p < 3; ++p) {
        floatx4 acc2[4];
        #pragma unroll
        for (int rt = 0; rt < 4; ++rt) acc2[rt] = zero4;

        const int n2 = p * 128 + cw;          // global GEMM2 column

        #pragma unroll
        for (int kc = 0; kc < 8; ++kc) {
            short8 a[4];
            #pragma unroll
            for (int rt = 0; rt < 4; ++rt)
                a[rt] = *(const short8*)(mbuf + (rt * 16 + l16) * MPITCH + kc * 32 + quad * 8);
            short8 b = *(const short8*)(w2 + (kc * 384 + n2) * 32 + quad * 8);
            #pragma unroll
            for (int rt = 0; rt < 4; ++rt)
                acc2[rt] = __builtin_amdgcn_mfma_f32_16x16x32_bf16(a[rt], b, acc2[rt], 0, 0, 0);
        }

        // ---- stage result (+bias) to LDS; C/D layout: col=l16, row=quad*4+reg ----
        const float bb = (p == 0) ? b_res[cw] : b_skip[n2 - 128];
        #pragma unroll
        for (int rt = 0; rt < 4; ++rt)
            #pragma unroll
            for (int i = 0; i < 4; ++i) {
                int row = rt * 16 + quad * 4 + i;
                obuf[row * OPITCH + cw] = acc2[rt][i] + bb;
            }
        __syncthreads();

        // ---- coalesced full-line NT store of the 64x128 plane ----
        if (p == 0) {
            // res: + x re-read (coalesced float4 rows; likely L2-warm from stage)
            for (int i = tid; i < ROWS * 32; i += 512) {
                int row = i >> 5;
                int c4  = (i & 31) << 2;
                size_t g = (size_t)(n0 + row);
                floatx4 v  = *(const floatx4*)(obuf + row * OPITCH + c4);
                floatx4 xv = *(const floatx4*)(x + g * 128 + c4);
                floatx4 o;
                o[0] = v[0] + xv[0]; o[1] = v[1] + xv[1];
                o[2] = v[2] + xv[2]; o[3] = v[3] + xv[3];
                __builtin_nontemporal_store(o, (floatx4*)(out + g * 128 + c4));
            }
        } else {
            const int cb = (p - 1) * 128;     // skip column base
            for (int i = tid; i < ROWS * 32; i += 512) {
                int row = i >> 5;
                int c4  = (i & 31) << 2;
                size_t g = (size_t)(n0 + row);
                floatx4 v = *(const floatx4*)(obuf + row * OPITCH + c4);
                __builtin_nontemporal_store(
                    v, (floatx4*)(out + (size_t)N_TOT * 128 + g * 256 + cb + c4));
            }
        }
        __syncthreads();   // obuf reuse guard for next pass
    }
}

extern "C" void kernel_launch(void* const* d_in, const int* in_sizes, int n_in,
                              void* d_out, int out_size, void* d_ws, size_t ws_size,
                              hipStream_t stream) {
    const float* x      = (const float*)d_in[0];
    const float* w_tanh = (const float*)d_in[1];
    const float* b_tanh = (const float*)d_in[2];
    const float* w_sig  = (const float*)d_in[3];
    const float* b_sig  = (const float*)d_in[4];
    const float* w_res  = (const float*)d_in[5];
    const float* b_res  = (const float*)d_in[6];
    const float* w_skip = (const float*)d_in[7];
    const float* b_skip = (const float*)d_in[8];

    ushort_t* w1 = (ushort_t*)d_ws;            // 8*512*32 = 131072 bf16 (256 KB)
    ushort_t* w2 = w1 + 8 * 512 * 32;          // 8*384*32 =  98304 bf16 (192 KB)
    float* out = (float*)d_out;

    // 131072 + 98304 = 229376 threads
    repack_w<<<896, 256, 0, stream>>>(w_tanh, w_sig, w_res, w_skip, w1, w2);
    fused_block<<<N_TOT / ROWS, 512, 0, stream>>>(x, b_tanh, b_sig, b_res, b_skip, w1, w2, out);
}